// Round 2
// baseline (921.637 us; speedup 1.0000x reference)
//
#include <hip/hip_runtime.h>
#include <hip/hip_bf16.h>
#include <math.h>

#define Ldim 16
#define BATCH 8
#define HWdim 1024

typedef __attribute__((ext_vector_type(8))) short s8v;
typedef __attribute__((ext_vector_type(4))) short s4v;
typedef __attribute__((ext_vector_type(2))) short s2v;
typedef __attribute__((ext_vector_type(4))) float f32x4;
typedef __attribute__((ext_vector_type(2))) float f32x2;

__device__ __forceinline__ short f2bf(float f) {
    __hip_bfloat16 h = __float2bfloat16(f);
    return __builtin_bit_cast(short, h);
}
__device__ __forceinline__ float bf2f(short s) {
    __hip_bfloat16 h = __builtin_bit_cast(__hip_bfloat16, s);
    return __bfloat162float(h);
}

// ---------------- prep: A_bar + bf16 weight repack ----------------
// X channel layout: ch = 2p+ri (re/im interleaved per state p).
// Wb[t][cout][u], cout = 2p+ri : step[p] * B_ri[p][u][t][ri]
// Wc[t][u][k],   k   = 2p+ri : (ri? -2 : 2) * C_ri[u][p][t][ri]
__global__ __launch_bounds__(256)
void prep_kernel(const float* __restrict__ Lre, const float* __restrict__ Lim,
                 const float* __restrict__ B_ri, const float* __restrict__ C_ri,
                 const float* __restrict__ log_step, short* __restrict__ Wb,
                 short* __restrict__ Wc, float* __restrict__ Abar) {
    int tid = blockIdx.x * 256 + threadIdx.x;
    if (tid < 256) {
        float st = expf(log_step[tid]);
        Abar[tid] = fminf(Lre[tid], -1e-4f) * st;
        Abar[256 + tid] = Lim[tid] * st;
    }
    const int total = 9 * 512 * 128;
    for (int i = tid; i < total; i += gridDim.x * 256) {
        {   // Wb: i = (t*512 + cout)*128 + u
            int u = i & 127;
            int tc = i >> 7;
            int cout = tc & 511;
            int t = tc >> 9;
            int p = cout >> 1, ri = cout & 1;
            float val = B_ri[(((size_t)p * 128 + u) * 9 + t) * 2 + ri] * expf(log_step[p]);
            Wb[i] = f2bf(val);
        }
        {   // Wc: i = (t*128 + u)*512 + k
            int k = i & 511;
            int tu = i >> 9;
            int uu = tu & 127;
            int t = tu >> 7;
            int p = k >> 1, ri = k & 1;
            float val = C_ri[(((size_t)uu * 256 + p) * 9 + t) * 2 + ri];
            val = ri ? -2.f * val : 2.f * val;
            Wc[i] = f2bf(val);
        }
    }
}

// ---------------- u -> bf16 once for all (L,B) ----------------
__global__ __launch_bounds__(256)
void ubf_kernel(const float* __restrict__ u, short* __restrict__ Ubf) {
    size_t t8 = ((size_t)blockIdx.x * 256 + threadIdx.x) * 8;
    f32x4 v0 = *(const f32x4*)(u + t8);
    f32x4 v1 = *(const f32x4*)(u + t8 + 4);
    s8v o;
#pragma unroll
    for (int j = 0; j < 4; ++j) { o[j] = f2bf(v0[j]); o[4 + j] = f2bf(v1[j]); }
    *(s8v*)(Ubf + t8) = o;
}

// ---------------- B-conv: CIN=128, COUT=512, all cout-groups in-block ----------------
// grid (8 rowgroups, imgs), block 256 = 4 waves (2M x 2N).
// The whole 6x34x128 input patch (both 64-ch chunks) is staged ONCE into 52KB
// LDS; the block then loops all 4 cout-groups over the resident patch.
// This cuts input HBM traffic 4x vs the old cgp-in-grid scheme (input read
// exactly once + halo). Weights (1.18MB) are L2-resident across all blocks.
template <bool INF32>
__global__ __launch_bounds__(256, 2)
void bconv_mfma(const void* __restrict__ inbuf, const short* __restrict__ Wt,
                short* __restrict__ outbuf, int b0, int Gshift) {
    constexpr int CIN = 128, COUT = 512;
    __shared__ short lds[2][6 * 34 * 64];  // [chunk][patch] = 52,224 B total

    const int tid = threadIdx.x;
    const int lane = tid & 63;
    const int wv = tid >> 6;
    const int waveM = wv & 1, waveN = wv >> 1;
    const int lm = lane & 15, quad = lane >> 4;
    const int h0 = blockIdx.x * 4;
    const int img = blockIdx.y;
    const int l = img >> Gshift;
    const int bi = img & ((1 << Gshift) - 1);
    const size_t inframe = (size_t)(l * BATCH + b0 + bi);

    // per-thread staging slots (6*34*8 = 1632 = 6*256+96)
    constexpr int NST = 7;
    uint goff[NST];
    int laddr[NST];
#pragma unroll
    for (int j = 0; j < NST; ++j) {
        int idx = tid + j * 256;
        laddr[j] = -1;
        goff[j] = 0xFFFFFFFFu;
        if (idx < 6 * 34 * 8) {
            int cgi = idx & 7;
            int pos = idx >> 3;
            int w34 = pos % 34;
            int sr = pos / 34;
            int habs = h0 - 1 + sr, wabs = w34 - 1;
            laddr[j] = ((pos << 3) + (cgi ^ (pos & 7))) << 3;
            if ((unsigned)habs < 32u && (unsigned)wabs < 32u)
                goff[j] = (uint)(((uint)inframe * HWdim + habs * 32 + wabs) * CIN + cgi * 8);
        }
    }

    // stage both chunks (one-time prologue, 14 outstanding 16B loads)
#pragma unroll
    for (int ch = 0; ch < 2; ++ch) {
        s8v sreg[NST];
#pragma unroll
        for (int j = 0; j < NST; ++j) {
            s8v v = (s8v){0, 0, 0, 0, 0, 0, 0, 0};
            if (goff[j] != 0xFFFFFFFFu) {
                if constexpr (INF32) {
                    const float* src = (const float*)inbuf + goff[j] + ch * 64;
                    f32x4 a0 = *(const f32x4*)src;
                    f32x4 a1 = *(const f32x4*)(src + 4);
#pragma unroll
                    for (int q = 0; q < 4; ++q) { v[q] = f2bf(a0[q]); v[4 + q] = f2bf(a1[q]); }
                } else {
                    v = *(const s8v*)((const short*)inbuf + goff[j] + ch * 64);
                }
            }
            sreg[j] = v;
        }
#pragma unroll
        for (int j = 0; j < NST; ++j)
            if (laddr[j] >= 0) *(s8v*)&lds[ch][laddr[j]] = sreg[j];
    }
    __syncthreads();

#pragma unroll 1
    for (int cgp = 0; cgp < 4; ++cgp) {
        f32x4 acc[4][4];
#pragma unroll
        for (int mt = 0; mt < 4; ++mt)
#pragma unroll
            for (int nt = 0; nt < 4; ++nt)
                acc[mt][nt] = (f32x4){0.f, 0.f, 0.f, 0.f};

#pragma unroll
        for (int ch = 0; ch < 2; ++ch) {
            const short* lb = &lds[ch][0];
            const short* wchunk =
                Wt + ((size_t)cgp * 128 + waveN * 64 + lm) * CIN + ch * 64 + quad * 8;

            auto loadA = [&](int s, s8v* a) {
                int t = s >> 1, ks = s & 1;
                int kh = t / 3, kw = t - kh * 3;
                int c = ks * 4 + quad;
#pragma unroll
                for (int mt = 0; mt < 4; ++mt) {
                    int p = (waveM * 2 + (mt >> 1) + kh) * 34 + (mt & 1) * 16 + lm + kw;
                    a[mt] = *(const s8v*)&lb[(((p << 3) + (c ^ (p & 7))) << 3)];
                }
            };
            auto loadB = [&](int s, s8v* b) {
                int t = s >> 1, ks = s & 1;
#pragma unroll
                for (int nt = 0; nt < 4; ++nt)
                    b[nt] = *(const s8v*)&wchunk[(size_t)t * COUT * CIN + nt * 16 * CIN + ks * 32];
            };

            s8v aC[4], bC[4];
            loadA(0, aC);
            loadB(0, bC);
#pragma unroll
            for (int s = 0; s < 18; ++s) {
                s8v aN[4], bN[4];
                if (s < 17) { loadA(s + 1, aN); loadB(s + 1, bN); }
                __builtin_amdgcn_s_setprio(1);
#pragma unroll
                for (int mt = 0; mt < 4; ++mt)
#pragma unroll
                    for (int nt = 0; nt < 4; ++nt)
                        acc[mt][nt] = __builtin_amdgcn_mfma_f32_16x16x32_bf16(
                            aC[mt], bC[nt], acc[mt][nt], 0, 0, 0);
                __builtin_amdgcn_s_setprio(0);
                if (s < 17) {
#pragma unroll
                    for (int r = 0; r < 4; ++r) { aC[r] = aN[r]; bC[r] = bN[r]; }
                }
            }
        }

        // epilogue for this cout-group: C/D row(m)=quad*4+reg, col(n)=lm
#pragma unroll
        for (int mt = 0; mt < 4; ++mt) {
#pragma unroll
            for (int reg = 0; reg < 4; ++reg) {
                int mm = waveM * 64 + mt * 16 + quad * 4 + reg;
                int r = mm >> 5, w = mm & 31;
                size_t rowbase = ((size_t)img * HWdim + (h0 + r) * 32 + w) * COUT +
                                 cgp * 128 + waveN * 64 + lm;
#pragma unroll
                for (int nt = 0; nt < 4; ++nt)
                    outbuf[rowbase + nt * 16] = f2bf(acc[mt][nt][reg]);
            }
        }
    }
}

// ---------------- MFMA implicit-GEMM 3x3 SAME conv (pipelined, C path) ----------------
// grid (8 rowgroups, COUT/128, 16*G imgs), block 256 = 4 waves (2M x 2N).
template <int CIN, int COUT, bool INF32, bool INFULL, bool RMW>
__global__ __launch_bounds__(256, 2)
void conv_mfma(const void* __restrict__ inbuf, const short* __restrict__ Wt,
               short* __restrict__ outbuf, int b0, int Gshift) {
    constexpr int NCH = CIN / 64;
    __shared__ short lds[2][6 * 34 * 64];  // 2 x 26,112 B

    const int tid = threadIdx.x;
    const int lane = tid & 63;
    const int wv = tid >> 6;
    const int waveM = wv & 1, waveN = wv >> 1;
    const int lm = lane & 15, quad = lane >> 4;
    const int h0 = blockIdx.x * 4;
    const int cgp = blockIdx.y;
    const int img = blockIdx.z;
    const int l = img >> Gshift;
    const int bi = img & ((1 << Gshift) - 1);
    const size_t inframe = INFULL ? (size_t)(l * BATCH + b0 + bi) : (size_t)img;

    constexpr int NST = 7;
    uint goff[NST];
    int laddr[NST];
#pragma unroll
    for (int j = 0; j < NST; ++j) {
        int idx = tid + j * 256;
        laddr[j] = -1;
        goff[j] = 0xFFFFFFFFu;
        if (idx < 6 * 34 * 8) {
            int cgi = idx & 7;
            int pos = idx >> 3;
            int w34 = pos % 34;
            int sr = pos / 34;
            int habs = h0 - 1 + sr, wabs = w34 - 1;
            laddr[j] = ((pos << 3) + (cgi ^ (pos & 7))) << 3;
            if ((unsigned)habs < 32u && (unsigned)wabs < 32u)
                goff[j] = (uint)(((uint)inframe * HWdim + habs * 32 + wabs) * CIN + cgi * 8);
        }
    }

    s8v sreg[NST];

    auto stage_load = [&](int ch) {
#pragma unroll
        for (int j = 0; j < NST; ++j) {
            s8v v = (s8v){0, 0, 0, 0, 0, 0, 0, 0};
            if (goff[j] != 0xFFFFFFFFu) {
                if constexpr (INF32) {
                    const float* src = (const float*)inbuf + goff[j] + ch * 64;
                    f32x4 a0 = *(const f32x4*)src;
                    f32x4 a1 = *(const f32x4*)(src + 4);
#pragma unroll
                    for (int q = 0; q < 4; ++q) { v[q] = f2bf(a0[q]); v[4 + q] = f2bf(a1[q]); }
                } else {
                    v = *(const s8v*)((const short*)inbuf + goff[j] + ch * 64);
                }
            }
            sreg[j] = v;
        }
    };
    auto stage_write = [&](int buf) {
#pragma unroll
        for (int j = 0; j < NST; ++j)
            if (laddr[j] >= 0) *(s8v*)&lds[buf][laddr[j]] = sreg[j];
    };

    f32x4 acc[4][4];
#pragma unroll
    for (int mt = 0; mt < 4; ++mt)
#pragma unroll
        for (int nt = 0; nt < 4; ++nt)
            acc[mt][nt] = (f32x4){0.f, 0.f, 0.f, 0.f};

    auto compute = [&](int ch) {
        const short* lb = &lds[ch & 1][0];
        const short* wchunk =
            Wt + ((size_t)cgp * 128 + waveN * 64 + lm) * CIN + ch * 64 + quad * 8;

        auto loadA = [&](int s, s8v* a) {
            int t = s >> 1, ks = s & 1;
            int kh = t / 3, kw = t - kh * 3;
            int c = ks * 4 + quad;
#pragma unroll
            for (int mt = 0; mt < 4; ++mt) {
                int p = (waveM * 2 + (mt >> 1) + kh) * 34 + (mt & 1) * 16 + lm + kw;
                a[mt] = *(const s8v*)&lb[(((p << 3) + (c ^ (p & 7))) << 3)];
            }
        };
        auto loadB = [&](int s, s8v* b) {
            int t = s >> 1, ks = s & 1;
#pragma unroll
            for (int nt = 0; nt < 4; ++nt)
                b[nt] = *(const s8v*)&wchunk[(size_t)t * COUT * CIN + nt * 16 * CIN + ks * 32];
        };

        s8v aC[4], bC[4];
        loadA(0, aC);
        loadB(0, bC);
#pragma unroll
        for (int s = 0; s < 18; ++s) {
            s8v aN[4], bN[4];
            if (s < 17) { loadA(s + 1, aN); loadB(s + 1, bN); }
            __builtin_amdgcn_s_setprio(1);
#pragma unroll
            for (int mt = 0; mt < 4; ++mt)
#pragma unroll
                for (int nt = 0; nt < 4; ++nt)
                    acc[mt][nt] = __builtin_amdgcn_mfma_f32_16x16x32_bf16(
                        aC[mt], bC[nt], acc[mt][nt], 0, 0, 0);
            __builtin_amdgcn_s_setprio(0);
            if (s < 17) {
#pragma unroll
                for (int r = 0; r < 4; ++r) { aC[r] = aN[r]; bC[r] = bN[r]; }
            }
        }
    };

    stage_load(0);
    stage_write(0);
    if (NCH > 1) stage_load(1);
    __syncthreads();

#pragma unroll 1
    for (int ch = 0; ch < NCH; ++ch) {
        compute(ch);
        if (ch + 1 < NCH) {
            stage_write((ch + 1) & 1);
            if (ch + 2 < NCH) stage_load(ch + 2);
            __syncthreads();
        }
    }

#pragma unroll
    for (int mt = 0; mt < 4; ++mt) {
#pragma unroll
        for (int reg = 0; reg < 4; ++reg) {
            int mm = waveM * 64 + mt * 16 + quad * 4 + reg;
            int r = mm >> 5, w = mm & 31;
            size_t rowbase = ((size_t)img * HWdim + (h0 + r) * 32 + w) * COUT +
                             cgp * 128 + waveN * 64 + lm;
#pragma unroll
            for (int nt = 0; nt < 4; ++nt) {
                size_t oidx = rowbase + nt * 16;
                float val = acc[mt][nt][reg];
                if (RMW) val += bf2f(outbuf[oidx]);
                outbuf[oidx] = f2bf(val);
            }
        }
    }
}

// ---------------- sequential diagonal scan, in-place on X, fp32 state ----------------
__global__ __launch_bounds__(256)
void scan_kernel(const float* __restrict__ x0, const float* __restrict__ Abar,
                 short* __restrict__ X, float* __restrict__ out_xlast, int b0, int G) {
    int p = threadIdx.x;
    int hw = blockIdx.x;
    int bi = blockIdx.y;
    int b = b0 + bi;
    float Ar = Abar[p], Ai = Abar[256 + p];
    float xr = x0[((size_t)b * HWdim + hw) * 256 + p];
    float xi = 0.f;
    for (int l = 0; l < Ldim; ++l) {
        size_t base = ((size_t)(l * G + bi) * HWdim + hw) * 512 + p * 2;
        s2v v = *(s2v*)&X[base];
        float br = bf2f(v[0]), bim = bf2f(v[1]);
        float nr = Ar * xr - Ai * xi + br;
        float ni = Ar * xi + Ai * xr + bim;
        xr = nr; xi = ni;
        v[0] = f2bf(xr); v[1] = f2bf(xi);
        *(s2v*)&X[base] = v;
    }
    f32x2 o2 = {xr, xi};
    *(f32x2*)&out_xlast[(((size_t)b * HWdim + hw) * 256 + p) * 2] = o2;
}

// ---------------- depthwise D conv -> ys (bf16), 4 ch/thread ----------------
template <bool UBF>
__global__ __launch_bounds__(256)
void du_kernel(const void* __restrict__ uin, const float* __restrict__ Dk,
               short* __restrict__ ys, int b0, int Gshift) {
    int tid = blockIdx.x * 256 + threadIdx.x;  // imgs*1024*32
    int c4 = tid & 31;
    int hw = (tid >> 5) & 1023;
    int img = tid >> 15;
    int h = hw >> 5, w = hw & 31;
    int l = img >> Gshift, bi = img & ((1 << Gshift) - 1);
    size_t fbase = ((size_t)(l * BATCH + b0 + bi)) * HWdim * 128;
    float s0 = 0.f, s1 = 0.f, s2 = 0.f, s3 = 0.f;
#pragma unroll
    for (int kh = 0; kh < 3; ++kh)
#pragma unroll
        for (int kw = 0; kw < 3; ++kw) {
            int hh = h + kh - 1, wc = w + kw - 1;
            if ((unsigned)hh < 32u && (unsigned)wc < 32u) {
                f32x4 d = *(const f32x4*)&Dk[(kh * 3 + kw) * 128 + c4 * 4];
                size_t off = fbase + ((size_t)hh * 32 + wc) * 128 + c4 * 4;
                if (UBF) {
                    s4v v = *(const s4v*)((const short*)uin + off);
                    s0 += bf2f(v[0]) * d[0]; s1 += bf2f(v[1]) * d[1];
                    s2 += bf2f(v[2]) * d[2]; s3 += bf2f(v[3]) * d[3];
                } else {
                    f32x4 v = *(const f32x4*)((const float*)uin + off);
                    s0 += v[0] * d[0]; s1 += v[1] * d[1];
                    s2 += v[2] * d[2]; s3 += v[3] * d[3];
                }
            }
        }
    s4v o = {f2bf(s0), f2bf(s1), f2bf(s2), f2bf(s3)};
    *(s4v*)&ys[(size_t)tid * 4] = o;
}

// ---------------- group norm stats per (img, group) ----------------
__global__ __launch_bounds__(256)
void gnstats_kernel(const short* __restrict__ ys, float* __restrict__ stats) {
    int g = blockIdx.x;
    int img = blockIdx.y;
    int tid = threadIdx.x;
    float s = 0.f, s2 = 0.f;
    for (int hw = tid; hw < HWdim; hw += 256) {
        s4v v = *(const s4v*)&ys[((size_t)img * HWdim + hw) * 128 + g * 4];
#pragma unroll
        for (int j = 0; j < 4; ++j) {
            float f = bf2f(v[j]);
            s += f; s2 += f * f;
        }
    }
    __shared__ float red[16];
    for (int off = 32; off > 0; off >>= 1) {
        s += __shfl_down(s, off, 64);
        s2 += __shfl_down(s2, off, 64);
    }
    int wid = tid >> 6;
    if ((tid & 63) == 0) { red[wid] = s; red[8 + wid] = s2; }
    __syncthreads();
    if (tid == 0) {
        float S = 0.f, S2 = 0.f;
        for (int w2 = 0; w2 < 4; ++w2) { S += red[w2]; S2 += red[8 + w2]; }
        const float inv = 1.f / (HWdim * 4);
        float mean = S * inv;
        float var = S2 * inv - mean * mean;
        stats[(img * 32 + g) * 2 + 0] = mean;
        stats[(img * 32 + g) * 2 + 1] = var;
    }
}

// ---------------- apply GN + gelu(tanh), 4 ch/thread ----------------
__global__ __launch_bounds__(256)
void gnapply_kernel(const short* __restrict__ ys, const float* __restrict__ stats,
                    const float* __restrict__ scale, const float* __restrict__ bias,
                    float* __restrict__ out_ys, int b0, int Gshift) {
    int tid = blockIdx.x * 256 + threadIdx.x;  // imgs*1024*32
    int c4 = tid & 31;
    int hw = (tid >> 5) & 1023;
    int img = tid >> 15;
    int l = img >> Gshift, bi = img & ((1 << Gshift) - 1);
    float mean = stats[(img * 32 + c4) * 2 + 0];
    float var = stats[(img * 32 + c4) * 2 + 1];
    float rstd = rsqrtf(var + 1e-5f);
    s4v v = *(const s4v*)&ys[(size_t)tid * 4];
    f32x4 sc = *(const f32x4*)&scale[c4 * 4];
    f32x4 bs = *(const f32x4*)&bias[c4 * 4];
    f32x4 o;
    const float kAlpha = 0.7978845608028654f;
#pragma unroll
    for (int j = 0; j < 4; ++j) {
        float y = (bf2f(v[j]) - mean) * rstd * sc[j] + bs[j];
        float t = kAlpha * (y + 0.044715f * y * y * y);
        o[j] = 0.5f * y * (1.f + tanhf(t));
    }
    *(f32x4*)&out_ys[(((size_t)(l * BATCH + b0 + bi)) * HWdim + hw) * 128 + c4 * 4] = o;
}

extern "C" void kernel_launch(void* const* d_in, const int* in_sizes, int n_in,
                              void* d_out, int out_size, void* d_ws, size_t ws_size,
                              hipStream_t stream) {
    const float* useq = (const float*)d_in[0];
    const float* x0 = (const float*)d_in[1];
    const float* Lre = (const float*)d_in[2];
    const float* Lim = (const float*)d_in[3];
    const float* B_ri = (const float*)d_in[4];
    const float* C_ri = (const float*)d_in[5];
    const float* log_step = (const float*)d_in[6];
    const float* Dk = (const float*)d_in[7];
    const float* gsc = (const float*)d_in[8];
    const float* gbi = (const float*)d_in[9];
    float* out = (float*)d_out;

    const size_t WBYTES = 9 * 512 * 128 * 2;       // 1,179,648
    const size_t UBF_BYTES = (size_t)Ldim * BATCH * HWdim * 128 * 2;  // 33,554,432

    // choose batch group G and whether to pre-convert u to bf16
    int G = 2;
    bool ubf = false;
    {
        auto need = [&](int g, bool u) -> size_t {
            size_t base = 2 * WBYTES + 2048 + (size_t)g * 4096;
            size_t x = (size_t)g * Ldim * HWdim * 512 * 2;
            size_t ysb = (size_t)g * Ldim * HWdim * 128 * 2;
            return base + x + ysb + (u ? UBF_BYTES : 0);
        };
        if (ws_size >= need(8, true)) { G = 8; ubf = true; }
        else if (ws_size >= need(8, false)) { G = 8; }
        else if (ws_size >= need(4, true)) { G = 4; ubf = true; }
        else if (ws_size >= need(4, false)) { G = 4; }
        else if (ws_size >= need(2, true)) { G = 2; ubf = true; }
    }
    int Gshift = (G == 8) ? 3 : (G == 4) ? 2 : 1;
    int imgs = Ldim * G;

    char* wsb = (char*)d_ws;
    short* Wb = (short*)(wsb);
    short* Wc = (short*)(wsb + WBYTES);
    float* Abar = (float*)(wsb + 2 * WBYTES);
    float* stats = (float*)(wsb + 2 * WBYTES + 2048);
    size_t offX = 2 * WBYTES + 2048 + (size_t)G * 4096;
    short* X = (short*)(wsb + offX);
    size_t offYS = offX + (size_t)G * Ldim * HWdim * 512 * 2;
    short* YS = (short*)(wsb + offYS);
    short* Ubf = (short*)(wsb + offYS + (size_t)G * Ldim * HWdim * 128 * 2);

    prep_kernel<<<2304, 256, 0, stream>>>(Lre, Lim, B_ri, C_ri, log_step, Wb, Wc, Abar);
    if (ubf) ubf_kernel<<<8192, 256, 0, stream>>>(useq, Ubf);

    for (int b0 = 0; b0 < BATCH; b0 += G) {
        // B conv: u (128ch) -> X (bf16, 512ch interleaved re/im), all couts per block
        if (ubf)
            bconv_mfma<false><<<dim3(8, imgs), 256, 0, stream>>>(Ubf, Wb, X, b0, Gshift);
        else
            bconv_mfma<true><<<dim3(8, imgs), 256, 0, stream>>>(useq, Wb, X, b0, Gshift);
        // scan over L in place, emits x_last fp32
        scan_kernel<<<dim3(HWdim, G), 256, 0, stream>>>(x0, Abar, X, out, b0, G);
        // depthwise feedthrough into ys
        if (ubf)
            du_kernel<true><<<imgs * 128, 256, 0, stream>>>(Ubf, Dk, YS, b0, Gshift);
        else
            du_kernel<false><<<imgs * 128, 256, 0, stream>>>(useq, Dk, YS, b0, Gshift);
        // C conv: X (512ch) -> ys += 2*Re(C conv x)  (RMW)
        conv_mfma<512, 128, false, false, true><<<dim3(8, 1, imgs), 256, 0, stream>>>(
            X, Wc, YS, b0, Gshift);
        gnstats_kernel<<<dim3(32, imgs), 256, 0, stream>>>(YS, stats);
        gnapply_kernel<<<imgs * 128, 256, 0, stream>>>(YS, stats, gsc, gbi, out + 4194304, b0,
                                                       Gshift);
    }
}

// Round 3
// 585.920 us; speedup vs baseline: 1.5730x; 1.5730x over previous
//
#include <hip/hip_runtime.h>
#include <hip/hip_bf16.h>
#include <math.h>

#define Ldim 16
#define BATCH 8
#define HWdim 1024

typedef __attribute__((ext_vector_type(8))) short s8v;
typedef __attribute__((ext_vector_type(4))) short s4v;
typedef __attribute__((ext_vector_type(2))) short s2v;
typedef __attribute__((ext_vector_type(4))) float f32x4;
typedef __attribute__((ext_vector_type(2))) float f32x2;

__device__ __forceinline__ short f2bf(float f) {
    __hip_bfloat16 h = __float2bfloat16(f);
    return __builtin_bit_cast(short, h);
}
__device__ __forceinline__ float bf2f(short s) {
    __hip_bfloat16 h = __builtin_bit_cast(__hip_bfloat16, s);
    return __bfloat162float(h);
}

// 16B global -> LDS DMA (wave-uniform LDS base + lane*16, per-lane global addr)
__device__ __forceinline__ void gload_lds16(const short* g, short* l) {
    __builtin_amdgcn_global_load_lds(
        (const __attribute__((address_space(1))) void*)g,
        (__attribute__((address_space(3))) void*)l, 16, 0, 0);
}

// ---------------- prep: A_bar + bf16 weight repack (TILED + SWIZZLED) ----------------
// Weights are stored as 16KB tiles of [cout_lc(128)][ci_local(64)] bf16, one tile
// per (cgp, ch, t), pre-swizzled so that a linear global_load_lds into LDS yields
// byte layout A = (cout_lc*128 + off) ^ ((cout_lc&7)<<4), making the MFMA B-frag
// ds_read_b128 (16 couts at 128B stride) bank-conflict-free.
// Wb tiles: [cgp(4)][ch(2)][t(9)]  cout = 2p+ri (re/im interleaved), ci = u
// Wc tiles: [ch(8)][t(9)]          cout = u, ci = k = 2p+ri
__global__ __launch_bounds__(256)
void prep_kernel(const float* __restrict__ Lre, const float* __restrict__ Lim,
                 const float* __restrict__ B_ri, const float* __restrict__ C_ri,
                 const float* __restrict__ log_step, short* __restrict__ Wb,
                 short* __restrict__ Wc, float* __restrict__ Abar) {
    int tid = blockIdx.x * 256 + threadIdx.x;
    if (tid < 256) {
        float st = expf(log_step[tid]);
        Abar[tid] = fminf(Lre[tid], -1e-4f) * st;
        Abar[256 + tid] = Lim[tid] * st;
    }
    const int total = 9 * 512 * 128;  // 589,824 shorts in each buffer
    for (int i = tid; i < total; i += gridDim.x * 256) {
        int tile = i >> 13;          // 8192 shorts per tile
        int r = i & 8191;
        int A = r * 2;               // byte addr within tile's LDS image
        int cout_lc = A >> 7;        // [0,128)
        int remb = A & 127;
        int ci2 = remb ^ ((cout_lc & 7) << 4);
        int ci_local = ci2 >> 1;     // [0,64)
        {   // Wb: tile = (cgp*2 + ch)*9 + t
            int cgp = tile / 18;
            int rm = tile % 18;
            int ch = rm / 9, t = rm % 9;
            int cout = cgp * 128 + cout_lc;
            int p = cout >> 1, ri = cout & 1;
            int u = ch * 64 + ci_local;
            float val = B_ri[(((size_t)p * 128 + u) * 9 + t) * 2 + ri] * expf(log_step[p]);
            Wb[i] = f2bf(val);
        }
        {   // Wc: tile = ch*9 + t
            int ch = tile / 9;
            int t = tile % 9;
            int u = cout_lc;
            int k = ch * 64 + ci_local;
            int p = k >> 1, ri = k & 1;
            float val = C_ri[(((size_t)u * 256 + p) * 9 + t) * 2 + ri];
            val = ri ? -2.f * val : 2.f * val;
            Wc[i] = f2bf(val);
        }
    }
}

// ---------------- u -> bf16 once for all (L,B) ----------------
__global__ __launch_bounds__(256)
void ubf_kernel(const float* __restrict__ u, short* __restrict__ Ubf) {
    size_t t8 = ((size_t)blockIdx.x * 256 + threadIdx.x) * 8;
    f32x4 v0 = *(const f32x4*)(u + t8);
    f32x4 v1 = *(const f32x4*)(u + t8 + 4);
    s8v o;
#pragma unroll
    for (int j = 0; j < 4; ++j) { o[j] = f2bf(v0[j]); o[4 + j] = f2bf(v1[j]); }
    *(s8v*)(Ubf + t8) = o;
}

// ---------------- MFMA implicit-GEMM 3x3 SAME conv ----------------
// grid (8 rowgroups, COUT/128, imgs), block 256 = 4 waves (2M x 2N).
// Block tile: 128 px x 128 couts. Input patch (26KB) staged per 64-ch chunk
// (synchronous, at chunk boundaries). Weights stream through a 3-deep LDS
// ring of 16KB tiles via global_load_lds, prefetched 2 taps ahead; tap
// boundaries use counted s_waitcnt vmcnt(4) + raw s_barrier so weight DMA
// stays in flight across barriers (never drained to 0 in the main loop).
template <int CIN, int COUT, bool INF32, bool INFULL, bool RMW>
__global__ __launch_bounds__(256, 2)
void conv_mfma(const void* __restrict__ inbuf, const short* __restrict__ Wt,
               short* __restrict__ outbuf, int b0, int Gshift) {
    constexpr int NCH = CIN / 64;
    constexpr int NT = NCH * 9;         // total (ch, tap) tiles
    __shared__ short ilds[6 * 34 * 64];  // 26,112 B input patch (one 64-ch chunk)
    __shared__ short wlds[3 * 8192];     // 49,152 B: 3 x 16KB weight tiles

    const int tid = threadIdx.x;
    const int lane = tid & 63;
    const int wv = tid >> 6;
    const int waveM = wv & 1, waveN = wv >> 1;
    const int lm = lane & 15, quad = lane >> 4;
    const int h0 = blockIdx.x * 4;
    const int cgp = blockIdx.y;
    const int img = blockIdx.z;
    const int l = img >> Gshift;
    const int bi = img & ((1 << Gshift) - 1);
    const size_t inframe = INFULL ? (size_t)(l * BATCH + b0 + bi) : (size_t)img;

    // per-thread input staging slots (6*34*8 = 1632 = 6*256+96)
    constexpr int NST = 7;
    uint goff[NST];
    int laddr[NST];
#pragma unroll
    for (int j = 0; j < NST; ++j) {
        int idx = tid + j * 256;
        laddr[j] = -1;
        goff[j] = 0xFFFFFFFFu;
        if (idx < 6 * 34 * 8) {
            int cgi = idx & 7;
            int pos = idx >> 3;
            int w34 = pos % 34;
            int sr = pos / 34;
            int habs = h0 - 1 + sr, wabs = w34 - 1;
            laddr[j] = ((pos << 3) + (cgi ^ (pos & 7))) << 3;
            if ((unsigned)habs < 32u && (unsigned)wabs < 32u)
                goff[j] = (uint)(((uint)inframe * HWdim + habs * 32 + wabs) * CIN + cgi * 8);
        }
    }

    // issue the 4 DMA loads for weight tile j into ring slot j%3
    auto issue_W = [&](int j) {
        const short* src = Wt + ((size_t)cgp * NT + j) * 8192;
        short* dst = &wlds[(j % 3) * 8192];
#pragma unroll
        for (int r = 0; r < 4; ++r)
            gload_lds16(src + (size_t)(r * 256 + tid) * 8, dst + (r * 256 + wv * 64) * 8);
    };

    // synchronous input-chunk staging (loads -> convert -> swizzled ds_write)
    auto stage_input = [&](int ch) {
        s8v sreg[NST];
#pragma unroll
        for (int j = 0; j < NST; ++j) {
            s8v v = (s8v){0, 0, 0, 0, 0, 0, 0, 0};
            if (goff[j] != 0xFFFFFFFFu) {
                if constexpr (INF32) {
                    const float* src = (const float*)inbuf + goff[j] + ch * 64;
                    f32x4 a0 = *(const f32x4*)src;
                    f32x4 a1 = *(const f32x4*)(src + 4);
#pragma unroll
                    for (int q = 0; q < 4; ++q) { v[q] = f2bf(a0[q]); v[4 + q] = f2bf(a1[q]); }
                } else {
                    v = *(const s8v*)((const short*)inbuf + goff[j] + ch * 64);
                }
            }
            sreg[j] = v;
        }
#pragma unroll
        for (int j = 0; j < NST; ++j)
            if (laddr[j] >= 0) *(s8v*)&ilds[laddr[j]] = sreg[j];
    };

    f32x4 acc[4][4];
#pragma unroll
    for (int mt = 0; mt < 4; ++mt)
#pragma unroll
        for (int nt = 0; nt < 4; ++nt)
            acc[mt][nt] = (f32x4){0.f, 0.f, 0.f, 0.f};

    // one tap: 2 ks-steps of {4 a-frag ds_reads, 4 b-frag ds_reads, 16 MFMA}
    auto compute_tap = [&](int t, const short* wb) {
        int kh = t / 3, kw = t - kh * 3;
#pragma unroll
        for (int ks = 0; ks < 2; ++ks) {
            s8v a[4], b[4];
#pragma unroll
            for (int mt = 0; mt < 4; ++mt) {
                int p = (waveM * 2 + (mt >> 1) + kh) * 34 + (mt & 1) * 16 + lm + kw;
                int c = ks * 4 + quad;
                a[mt] = *(const s8v*)&ilds[(((p << 3) + (c ^ (p & 7))) << 3)];
            }
#pragma unroll
            for (int nt = 0; nt < 4; ++nt) {
                int cl = waveN * 64 + nt * 16 + lm;
                int ba = (cl * 128 + ks * 64 + quad * 16) ^ ((cl & 7) << 4);
                b[nt] = *(const s8v*)((const char*)wb + ba);
            }
            __builtin_amdgcn_s_setprio(1);
#pragma unroll
            for (int mt = 0; mt < 4; ++mt)
#pragma unroll
                for (int nt = 0; nt < 4; ++nt)
                    acc[mt][nt] = __builtin_amdgcn_mfma_f32_16x16x32_bf16(
                        a[mt], b[nt], acc[mt][nt], 0, 0, 0);
            __builtin_amdgcn_s_setprio(0);
        }
    };

    // prologue: issue W0,W1; stage input chunk 0; full drain once; barrier
    issue_W(0);
    if (NT > 1) issue_W(1);
    stage_input(0);
    asm volatile("s_waitcnt vmcnt(0) lgkmcnt(0)" ::: "memory");
    __builtin_amdgcn_sched_barrier(0);
    __builtin_amdgcn_s_barrier();

#pragma unroll
    for (int k = 0; k < NT; ++k) {
        const int ch = k / 9;
        const int t = k - ch * 9;
        if (k + 2 < NT) issue_W(k + 2);
        compute_tap(t, &wlds[(k % 3) * 8192]);
        if (k + 1 < NT) {
            // tile k+1 must be resident; tile k+2 (4 DMA ops) may stay in flight
            if (k + 2 < NT) {
                asm volatile("s_waitcnt vmcnt(4)" ::: "memory");
            } else {
                asm volatile("s_waitcnt vmcnt(0)" ::: "memory");
            }
            __builtin_amdgcn_sched_barrier(0);
            __builtin_amdgcn_s_barrier();
            if (t == 8) {  // chunk boundary: restage input patch
                stage_input(ch + 1);
                asm volatile("s_waitcnt lgkmcnt(0)" ::: "memory");
                __builtin_amdgcn_sched_barrier(0);
                __builtin_amdgcn_s_barrier();
            }
        }
    }

    // epilogue: C/D row(m)=quad*4+reg (pixel), col(n)=lm (cout)
#pragma unroll
    for (int mt = 0; mt < 4; ++mt) {
#pragma unroll
        for (int reg = 0; reg < 4; ++reg) {
            int mm = waveM * 64 + mt * 16 + quad * 4 + reg;
            int r = mm >> 5, w = mm & 31;
            size_t rowbase = ((size_t)img * HWdim + (h0 + r) * 32 + w) * COUT +
                             cgp * 128 + waveN * 64 + lm;
#pragma unroll
            for (int nt = 0; nt < 4; ++nt) {
                size_t oidx = rowbase + nt * 16;
                float val = acc[mt][nt][reg];
                if (RMW) val += bf2f(outbuf[oidx]);
                outbuf[oidx] = f2bf(val);
            }
        }
    }
}

// ---------------- sequential diagonal scan, in-place on X, fp32 state ----------------
__global__ __launch_bounds__(256)
void scan_kernel(const float* __restrict__ x0, const float* __restrict__ Abar,
                 short* __restrict__ X, float* __restrict__ out_xlast, int b0, int G) {
    int p = threadIdx.x;
    int hw = blockIdx.x;
    int bi = blockIdx.y;
    int b = b0 + bi;
    float Ar = Abar[p], Ai = Abar[256 + p];
    float xr = x0[((size_t)b * HWdim + hw) * 256 + p];
    float xi = 0.f;
    for (int l = 0; l < Ldim; ++l) {
        size_t base = ((size_t)(l * G + bi) * HWdim + hw) * 512 + p * 2;
        s2v v = *(s2v*)&X[base];
        float br = bf2f(v[0]), bim = bf2f(v[1]);
        float nr = Ar * xr - Ai * xi + br;
        float ni = Ar * xi + Ai * xr + bim;
        xr = nr; xi = ni;
        v[0] = f2bf(xr); v[1] = f2bf(xi);
        *(s2v*)&X[base] = v;
    }
    f32x2 o2 = {xr, xi};
    *(f32x2*)&out_xlast[(((size_t)b * HWdim + hw) * 256 + p) * 2] = o2;
}

// ---------------- depthwise D conv -> ys (bf16), 4 ch/thread ----------------
template <bool UBF>
__global__ __launch_bounds__(256)
void du_kernel(const void* __restrict__ uin, const float* __restrict__ Dk,
               short* __restrict__ ys, int b0, int Gshift) {
    int tid = blockIdx.x * 256 + threadIdx.x;  // imgs*1024*32
    int c4 = tid & 31;
    int hw = (tid >> 5) & 1023;
    int img = tid >> 15;
    int h = hw >> 5, w = hw & 31;
    int l = img >> Gshift, bi = img & ((1 << Gshift) - 1);
    size_t fbase = ((size_t)(l * BATCH + b0 + bi)) * HWdim * 128;
    float s0 = 0.f, s1 = 0.f, s2 = 0.f, s3 = 0.f;
#pragma unroll
    for (int kh = 0; kh < 3; ++kh)
#pragma unroll
        for (int kw = 0; kw < 3; ++kw) {
            int hh = h + kh - 1, wc = w + kw - 1;
            if ((unsigned)hh < 32u && (unsigned)wc < 32u) {
                f32x4 d = *(const f32x4*)&Dk[(kh * 3 + kw) * 128 + c4 * 4];
                size_t off = fbase + ((size_t)hh * 32 + wc) * 128 + c4 * 4;
                if (UBF) {
                    s4v v = *(const s4v*)((const short*)uin + off);
                    s0 += bf2f(v[0]) * d[0]; s1 += bf2f(v[1]) * d[1];
                    s2 += bf2f(v[2]) * d[2]; s3 += bf2f(v[3]) * d[3];
                } else {
                    f32x4 v = *(const f32x4*)((const float*)uin + off);
                    s0 += v[0] * d[0]; s1 += v[1] * d[1];
                    s2 += v[2] * d[2]; s3 += v[3] * d[3];
                }
            }
        }
    s4v o = {f2bf(s0), f2bf(s1), f2bf(s2), f2bf(s3)};
    *(s4v*)&ys[(size_t)tid * 4] = o;
}

// ---------------- group norm stats per (img, group) ----------------
__global__ __launch_bounds__(256)
void gnstats_kernel(const short* __restrict__ ys, float* __restrict__ stats) {
    int g = blockIdx.x;
    int img = blockIdx.y;
    int tid = threadIdx.x;
    float s = 0.f, s2 = 0.f;
    for (int hw = tid; hw < HWdim; hw += 256) {
        s4v v = *(const s4v*)&ys[((size_t)img * HWdim + hw) * 128 + g * 4];
#pragma unroll
        for (int j = 0; j < 4; ++j) {
            float f = bf2f(v[j]);
            s += f; s2 += f * f;
        }
    }
    __shared__ float red[16];
    for (int off = 32; off > 0; off >>= 1) {
        s += __shfl_down(s, off, 64);
        s2 += __shfl_down(s2, off, 64);
    }
    int wid = tid >> 6;
    if ((tid & 63) == 0) { red[wid] = s; red[8 + wid] = s2; }
    __syncthreads();
    if (tid == 0) {
        float S = 0.f, S2 = 0.f;
        for (int w2 = 0; w2 < 4; ++w2) { S += red[w2]; S2 += red[8 + w2]; }
        const float inv = 1.f / (HWdim * 4);
        float mean = S * inv;
        float var = S2 * inv - mean * mean;
        stats[(img * 32 + g) * 2 + 0] = mean;
        stats[(img * 32 + g) * 2 + 1] = var;
    }
}

// ---------------- apply GN + gelu(tanh), 4 ch/thread ----------------
__global__ __launch_bounds__(256)
void gnapply_kernel(const short* __restrict__ ys, const float* __restrict__ stats,
                    const float* __restrict__ scale, const float* __restrict__ bias,
                    float* __restrict__ out_ys, int b0, int Gshift) {
    int tid = blockIdx.x * 256 + threadIdx.x;  // imgs*1024*32
    int c4 = tid & 31;
    int hw = (tid >> 5) & 1023;
    int img = tid >> 15;
    int l = img >> Gshift, bi = img & ((1 << Gshift) - 1);
    float mean = stats[(img * 32 + c4) * 2 + 0];
    float var = stats[(img * 32 + c4) * 2 + 1];
    float rstd = rsqrtf(var + 1e-5f);
    s4v v = *(const s4v*)&ys[(size_t)tid * 4];
    f32x4 sc = *(const f32x4*)&scale[c4 * 4];
    f32x4 bs = *(const f32x4*)&bias[c4 * 4];
    f32x4 o;
    const float kAlpha = 0.7978845608028654f;
#pragma unroll
    for (int j = 0; j < 4; ++j) {
        float y = (bf2f(v[j]) - mean) * rstd * sc[j] + bs[j];
        float t = kAlpha * (y + 0.044715f * y * y * y);
        o[j] = 0.5f * y * (1.f + tanhf(t));
    }
    *(f32x4*)&out_ys[(((size_t)(l * BATCH + b0 + bi)) * HWdim + hw) * 128 + c4 * 4] = o;
}

extern "C" void kernel_launch(void* const* d_in, const int* in_sizes, int n_in,
                              void* d_out, int out_size, void* d_ws, size_t ws_size,
                              hipStream_t stream) {
    const float* useq = (const float*)d_in[0];
    const float* x0 = (const float*)d_in[1];
    const float* Lre = (const float*)d_in[2];
    const float* Lim = (const float*)d_in[3];
    const float* B_ri = (const float*)d_in[4];
    const float* C_ri = (const float*)d_in[5];
    const float* log_step = (const float*)d_in[6];
    const float* Dk = (const float*)d_in[7];
    const float* gsc = (const float*)d_in[8];
    const float* gbi = (const float*)d_in[9];
    float* out = (float*)d_out;

    const size_t WBYTES = 9 * 512 * 128 * 2;       // 1,179,648
    const size_t UBF_BYTES = (size_t)Ldim * BATCH * HWdim * 128 * 2;  // 33,554,432

    // choose batch group G and whether to pre-convert u to bf16
    int G = 2;
    bool ubf = false;
    {
        auto need = [&](int g, bool u) -> size_t {
            size_t base = 2 * WBYTES + 2048 + (size_t)g * 4096;
            size_t x = (size_t)g * Ldim * HWdim * 512 * 2;
            size_t ysb = (size_t)g * Ldim * HWdim * 128 * 2;
            return base + x + ysb + (u ? UBF_BYTES : 0);
        };
        if (ws_size >= need(8, true)) { G = 8; ubf = true; }
        else if (ws_size >= need(8, false)) { G = 8; }
        else if (ws_size >= need(4, true)) { G = 4; ubf = true; }
        else if (ws_size >= need(4, false)) { G = 4; }
        else if (ws_size >= need(2, true)) { G = 2; ubf = true; }
    }
    int Gshift = (G == 8) ? 3 : (G == 4) ? 2 : 1;
    int imgs = Ldim * G;

    char* wsb = (char*)d_ws;
    short* Wb = (short*)(wsb);
    short* Wc = (short*)(wsb + WBYTES);
    float* Abar = (float*)(wsb + 2 * WBYTES);
    float* stats = (float*)(wsb + 2 * WBYTES + 2048);
    size_t offX = 2 * WBYTES + 2048 + (size_t)G * 4096;
    short* X = (short*)(wsb + offX);
    size_t offYS = offX + (size_t)G * Ldim * HWdim * 512 * 2;
    short* YS = (short*)(wsb + offYS);
    short* Ubf = (short*)(wsb + offYS + (size_t)G * Ldim * HWdim * 128 * 2);

    prep_kernel<<<2304, 256, 0, stream>>>(Lre, Lim, B_ri, C_ri, log_step, Wb, Wc, Abar);
    if (ubf) ubf_kernel<<<8192, 256, 0, stream>>>(useq, Ubf);

    for (int b0 = 0; b0 < BATCH; b0 += G) {
        // B conv: u (128ch) -> X (bf16, 512ch interleaved re/im)
        if (ubf)
            conv_mfma<128, 512, false, true, false><<<dim3(8, 4, imgs), 256, 0, stream>>>(
                Ubf, Wb, X, b0, Gshift);
        else
            conv_mfma<128, 512, true, true, false><<<dim3(8, 4, imgs), 256, 0, stream>>>(
                useq, Wb, X, b0, Gshift);
        // scan over L in place, emits x_last fp32
        scan_kernel<<<dim3(HWdim, G), 256, 0, stream>>>(x0, Abar, X, out, b0, G);
        // depthwise feedthrough into ys
        if (ubf)
            du_kernel<true><<<imgs * 128, 256, 0, stream>>>(Ubf, Dk, YS, b0, Gshift);
        else
            du_kernel<false><<<imgs * 128, 256, 0, stream>>>(useq, Dk, YS, b0, Gshift);
        // C conv: X (512ch) -> ys += 2*Re(C conv x)  (RMW)
        conv_mfma<512, 128, false, false, true><<<dim3(8, 1, imgs), 256, 0, stream>>>(
            X, Wc, YS, b0, Gshift);
        gnstats_kernel<<<dim3(32, imgs), 256, 0, stream>>>(YS, stats);
        gnapply_kernel<<<imgs * 128, 256, 0, stream>>>(YS, stats, gsc, gbi, out + 4194304, b0,
                                                       Gshift);
    }
}